// Round 3
// baseline (1115.963 us; speedup 1.0000x reference)
//
#include <hip/hip_runtime.h>
#include <math.h>

#define B_ 1024
#define N_ 64
#define DIN 64
#define HID 128
#define HEADS 4
#define EPG 512                 // edges per graph (448 rand + 64 self loops)
#define VTOT (B_ * N_)          // 65536
#define ETOT (B_ * EPG)         // 524288
#define LN_EPS 1e-5f
#define NEG_SLOPE 0.2f

// CSR of the (shared) edge template: off[65], srcs[512] sorted by dst
__device__ int g_off[65];
__device__ int g_srcs[EPG];

__device__ __forceinline__ float wave_sum(float v) {
#pragma unroll
    for (int o = 32; o > 0; o >>= 1) v += __shfl_xor(v, o);
    return v;
}

// ---------- K0: build template CSR once (1 block, 512 threads) ----------
__global__ void k_prep(const int* __restrict__ edge_index) {
    __shared__ unsigned cnt[64], cur[64];
    __shared__ int soff[65];
    const int t = threadIdx.x;          // one edge per thread
    if (t < 64) cnt[t] = 0u;
    __syncthreads();
    const int sv = edge_index[t];           // graph 0 == template
    const int dv = edge_index[ETOT + t];
    atomicAdd(&cnt[dv], 1u);
    __syncthreads();
    if (t == 0) {
        int a = 0;
        for (int v = 0; v < 64; ++v) { soff[v] = a; cur[v] = (unsigned)a; a += (int)cnt[v]; }
        soff[64] = a;
    }
    __syncthreads();
    const unsigned p = atomicAdd(&cur[dv], 1u);
    g_srcs[p] = sv;
    if (t < 65) g_off[t] = soff[t];
}

// ---------- K1: align Linear(64->128) + LayerNorm + sigmoid gate ----------
// block = 256 threads = 4 waves; each wave handles 4 nodes (16 nodes/block)
__global__ __launch_bounds__(256) void k_align(
    const float* __restrict__ fv, const float* __restrict__ W,
    const float* __restrict__ bias, const float* __restrict__ gamma,
    const float* __restrict__ beta, const float* __restrict__ ml,
    float* __restrict__ x, float* __restrict__ gate_out)
{
    __shared__ float sfv[16][DIN];
    const int t = threadIdx.x;
    const int lane = t & 63, wid = t >> 6;
    const int vbase = blockIdx.x * 16;

    ((float4*)sfv)[t] = ((const float4*)(fv + (size_t)vbase * DIN))[t];
    __syncthreads();

    float acc[4][2];
#pragma unroll
    for (int n = 0; n < 4; ++n) { acc[n][0] = 0.f; acc[n][1] = 0.f; }

    const int nb = wid * 4;
#pragma unroll 8
    for (int k = 0; k < DIN; ++k) {
        const float wlo = W[k * HID + lane];
        const float whi = W[k * HID + 64 + lane];
#pragma unroll
        for (int n = 0; n < 4; ++n) {
            const float f = sfv[nb + n][k];
            acc[n][0] += f * wlo;
            acc[n][1] += f * whi;
        }
    }

    const float blo = bias[lane],  bhi = bias[64 + lane];
    const float glo = gamma[lane], ghi = gamma[64 + lane];
    const float belo = beta[lane], behi = beta[64 + lane];
#pragma unroll
    for (int n = 0; n < 4; ++n) {
        const int v = vbase + nb + n;
        const float a0 = acc[n][0] + blo, a1 = acc[n][1] + bhi;
        const float mu = wave_sum(a0 + a1) * (1.f / HID);
        const float c0v = a0 - mu, c1v = a1 - mu;
        const float var = wave_sum(c0v * c0v + c1v * c1v) * (1.f / HID);
        const float rstd = rsqrtf(var + LN_EPS);
        const float gte = 1.f / (1.f + expf(-ml[v & 63]));
        x[(size_t)v * HID + lane]      = (c0v * rstd * glo + belo) * gte;
        x[(size_t)v * HID + 64 + lane] = (c1v * rstd * ghi + behi) * gte;
    }
    if (blockIdx.x == 0 && t < N_) gate_out[t] = 1.f / (1.f + expf(-ml[t]));
}

// ---------- K2: GAT layer 1 fused: GEMM(128x128 per head) + softmax + agg + ELU ----------
// grid = B*HEADS; block (g,h), 512 threads
__global__ __launch_bounds__(512, 4) void k_gat1(
    const float* __restrict__ x, const float* __restrict__ W1,
    const float* __restrict__ att_src1, const float* __restrict__ att_dst1,
    const float* __restrict__ bias1, float* __restrict__ x1)
{
    __shared__ float sx[64][HID];       // x tile, reused in-place as h
    __shared__ float sW[32][HID];       // W1 K-chunk
    __shared__ float s_alpha[EPG];
    __shared__ short s_srcs[EPG];
    __shared__ int   s_off[65];
    __shared__ float sa_src[64], sa_dst[64], s_den[64];

    const int t = threadIdx.x;
    const int g = blockIdx.x >> 2, h = blockIdx.x & 3;
    const int hbase = h * HID;

    // stage x tile (flat copy) + CSR
    {
        const float4* src4 = (const float4*)(x + (size_t)g * (64 * HID));
        float4* dst4 = (float4*)&sx[0][0];
#pragma unroll
        for (int j = 0; j < 4; ++j) dst4[t + j * 512] = src4[t + j * 512];
        s_srcs[t] = (short)g_srcs[t];
        if (t < 65) s_off[t] = g_off[t];
    }

    // GEMM: h[64][128] = sx @ W1[:, hbase:hbase+128], W staged in 4 chunks of 32 rows
    const int c0 = (t & 31) * 4;
    const int r0 = (t >> 5) * 4;
    float acc[4][4];
#pragma unroll
    for (int i = 0; i < 4; ++i)
#pragma unroll
        for (int j = 0; j < 4; ++j) acc[i][j] = 0.f;

    for (int kc = 0; kc < 4; ++kc) {
        __syncthreads();
        {
            const int i0 = t, i1 = t + 512;
            ((float4*)&sW[0][0])[i0] =
                *(const float4*)&W1[(size_t)(kc * 32 + (i0 >> 5)) * (HEADS * HID) + hbase + (i0 & 31) * 4];
            ((float4*)&sW[0][0])[i1] =
                *(const float4*)&W1[(size_t)(kc * 32 + (i1 >> 5)) * (HEADS * HID) + hbase + (i1 & 31) * 4];
        }
        __syncthreads();
#pragma unroll
        for (int kk = 0; kk < 32; kk += 4) {
            const float4 w0 = *(const float4*)&sW[kk + 0][c0];
            const float4 w1 = *(const float4*)&sW[kk + 1][c0];
            const float4 w2 = *(const float4*)&sW[kk + 2][c0];
            const float4 w3 = *(const float4*)&sW[kk + 3][c0];
            const int k = kc * 32 + kk;
#pragma unroll
            for (int i = 0; i < 4; ++i) {
                const float4 xv = *(const float4*)&sx[r0 + i][k];
                acc[i][0] += xv.x * w0.x + xv.y * w1.x + xv.z * w2.x + xv.w * w3.x;
                acc[i][1] += xv.x * w0.y + xv.y * w1.y + xv.z * w2.y + xv.w * w3.y;
                acc[i][2] += xv.x * w0.z + xv.y * w1.z + xv.z * w2.z + xv.w * w3.z;
                acc[i][3] += xv.x * w0.w + xv.y * w1.w + xv.z * w2.w + xv.w * w3.w;
            }
        }
    }
    __syncthreads();
#pragma unroll
    for (int i = 0; i < 4; ++i)
        *(float4*)&sx[r0 + i][c0] = make_float4(acc[i][0], acc[i][1], acc[i][2], acc[i][3]);
    __syncthreads();

    // per-node attention coefficients (wave per 8 nodes, conflict-free row reads)
    const int lane = t & 63, wid = t >> 6;
    {
        const float as0 = att_src1[hbase + lane], as1 = att_src1[hbase + 64 + lane];
        const float ad0 = att_dst1[hbase + lane], ad1 = att_dst1[hbase + 64 + lane];
#pragma unroll
        for (int i = wid * 8; i < wid * 8 + 8; ++i) {
            const float h0 = sx[i][lane], h1 = sx[i][64 + lane];
            const float vs = wave_sum(h0 * as0 + h1 * as1);
            const float vd = wave_sum(h0 * ad0 + h1 * ad1);
            if (lane == 0) { sa_src[i] = vs; sa_dst[i] = vd; }
        }
    }
    __syncthreads();

    // atomic-free segment softmax: one thread per dst walks its CSR segment
    if (t < 64) {
        const int b = s_off[t], e2 = s_off[t + 1];
        const float sad = sa_dst[t];
        float mx = -1e30f;
        for (int i = b; i < e2; ++i) {
            float sc = sa_src[s_srcs[i]] + sad;
            sc = sc > 0.f ? sc : NEG_SLOPE * sc;
            s_alpha[i] = sc;
            mx = fmaxf(mx, sc);
        }
        float den = 0.f;
        for (int i = b; i < e2; ++i) {
            const float ex = expf(s_alpha[i] - mx);
            s_alpha[i] = ex;
            den += ex;
        }
        s_den[t] = 1.f / (den + 1e-16f);
    }
    __syncthreads();

    // aggregation + bias + ELU + store (16 dst-groups x 32 lanes x float4)
    const int grp = t >> 5, l32 = t & 31;
    const int cagg = l32 * 4;
    const float4 bv = *(const float4*)&bias1[hbase + cagg];
    for (int d = grp; d < 64; d += 16) {
        const int b = s_off[d], e2 = s_off[d + 1];
        const float rden = s_den[d];
        float a0 = 0.f, a1 = 0.f, a2 = 0.f, a3 = 0.f;
        for (int i = b; i < e2; ++i) {
            const float al = s_alpha[i];
            const float4 hv = *(const float4*)&sx[s_srcs[i]][cagg];
            a0 += al * hv.x; a1 += al * hv.y; a2 += al * hv.z; a3 += al * hv.w;
        }
        float4 o;
        o.x = a0 * rden + bv.x; o.y = a1 * rden + bv.y;
        o.z = a2 * rden + bv.z; o.w = a3 * rden + bv.w;
        o.x = o.x > 0.f ? o.x : expm1f(o.x);
        o.y = o.y > 0.f ? o.y : expm1f(o.y);
        o.z = o.z > 0.f ? o.z : expm1f(o.z);
        o.w = o.w > 0.f ? o.w : expm1f(o.w);
        *(float4*)&x1[((size_t)g * 64 + d) * (HEADS * HID) + hbase + cagg] = o;
    }
}

// ---------- K3: GAT layer 2 (512->128, 1 head) + mean pool ----------
// grid = B; block g, 512 threads
__global__ __launch_bounds__(512, 4) void k_gat2(
    const float* __restrict__ x1, const float* __restrict__ W2,
    const float* __restrict__ att_src2, const float* __restrict__ att_dst2,
    const float* __restrict__ bias2, float* __restrict__ out)
{
    __shared__ float schunk[64][HID];   // x1 K-chunk, reused in-place as h
    __shared__ float sW[32][HID];       // W2 K-chunk; later reused as pool buffer
    __shared__ float s_alpha[EPG];
    __shared__ short s_srcs[EPG];
    __shared__ int   s_off[65];
    __shared__ float sa_src[64], sa_dst[64], s_den[64];

    const int t = threadIdx.x;
    const int g = blockIdx.x;

    s_srcs[t] = (short)g_srcs[t];
    if (t < 65) s_off[t] = g_off[t];

    const int c0 = (t & 31) * 4;
    const int r0 = (t >> 5) * 4;
    float acc[4][4];
#pragma unroll
    for (int i = 0; i < 4; ++i)
#pragma unroll
        for (int j = 0; j < 4; ++j) acc[i][j] = 0.f;

    for (int c = 0; c < 4; ++c) {
        __syncthreads();
        {
            const float* src = x1 + (size_t)g * (64 * 512) + c * HID;
#pragma unroll
            for (int j = 0; j < 4; ++j) {
                const int idx = t + j * 512;
                const int r = idx >> 5, c4 = idx & 31;
                *(float4*)&schunk[r][c4 * 4] = *(const float4*)&src[(size_t)r * 512 + c4 * 4];
            }
        }
        for (int kc = 0; kc < 4; ++kc) {
            __syncthreads();
            {
                const int i0 = t, i1 = t + 512;
                ((float4*)&sW[0][0])[i0] =
                    *(const float4*)&W2[(size_t)(c * 128 + kc * 32 + (i0 >> 5)) * HID + (i0 & 31) * 4];
                ((float4*)&sW[0][0])[i1] =
                    *(const float4*)&W2[(size_t)(c * 128 + kc * 32 + (i1 >> 5)) * HID + (i1 & 31) * 4];
            }
            __syncthreads();
#pragma unroll
            for (int kk = 0; kk < 32; kk += 4) {
                const float4 w0 = *(const float4*)&sW[kk + 0][c0];
                const float4 w1 = *(const float4*)&sW[kk + 1][c0];
                const float4 w2 = *(const float4*)&sW[kk + 2][c0];
                const float4 w3 = *(const float4*)&sW[kk + 3][c0];
                const int k = kc * 32 + kk;
#pragma unroll
                for (int i = 0; i < 4; ++i) {
                    const float4 xv = *(const float4*)&schunk[r0 + i][k];
                    acc[i][0] += xv.x * w0.x + xv.y * w1.x + xv.z * w2.x + xv.w * w3.x;
                    acc[i][1] += xv.x * w0.y + xv.y * w1.y + xv.z * w2.y + xv.w * w3.y;
                    acc[i][2] += xv.x * w0.z + xv.y * w1.z + xv.z * w2.z + xv.w * w3.z;
                    acc[i][3] += xv.x * w0.w + xv.y * w1.w + xv.z * w2.w + xv.w * w3.w;
                }
            }
        }
    }
    __syncthreads();
#pragma unroll
    for (int i = 0; i < 4; ++i)
        *(float4*)&schunk[r0 + i][c0] = make_float4(acc[i][0], acc[i][1], acc[i][2], acc[i][3]);
    __syncthreads();

    const int lane = t & 63, wid = t >> 6;
    {
        const float as0 = att_src2[lane], as1 = att_src2[64 + lane];
        const float ad0 = att_dst2[lane], ad1 = att_dst2[64 + lane];
#pragma unroll
        for (int i = wid * 8; i < wid * 8 + 8; ++i) {
            const float h0 = schunk[i][lane], h1 = schunk[i][64 + lane];
            const float vs = wave_sum(h0 * as0 + h1 * as1);
            const float vd = wave_sum(h0 * ad0 + h1 * ad1);
            if (lane == 0) { sa_src[i] = vs; sa_dst[i] = vd; }
        }
    }
    __syncthreads();

    if (t < 64) {
        const int b = s_off[t], e2 = s_off[t + 1];
        const float sad = sa_dst[t];
        float mx = -1e30f;
        for (int i = b; i < e2; ++i) {
            float sc = sa_src[s_srcs[i]] + sad;
            sc = sc > 0.f ? sc : NEG_SLOPE * sc;
            s_alpha[i] = sc;
            mx = fmaxf(mx, sc);
        }
        float den = 0.f;
        for (int i = b; i < e2; ++i) {
            const float ex = expf(s_alpha[i] - mx);
            s_alpha[i] = ex;
            den += ex;
        }
        s_den[t] = 1.f / (den + 1e-16f);
    }
    __syncthreads();

    // aggregation + mean pool (bias2 added once after pooling; biases commute with mean)
    const int grp = t >> 5, l32 = t & 31;
    const int cagg = l32 * 4;
    float p0 = 0.f, p1 = 0.f, p2 = 0.f, p3 = 0.f;
    for (int d = grp; d < 64; d += 16) {
        const int b = s_off[d], e2 = s_off[d + 1];
        const float rden = s_den[d];
        float a0 = 0.f, a1 = 0.f, a2 = 0.f, a3 = 0.f;
        for (int i = b; i < e2; ++i) {
            const float al = s_alpha[i];
            const float4 hv = *(const float4*)&schunk[s_srcs[i]][cagg];
            a0 += al * hv.x; a1 += al * hv.y; a2 += al * hv.z; a3 += al * hv.w;
        }
        p0 += a0 * rden; p1 += a1 * rden; p2 += a2 * rden; p3 += a3 * rden;
    }
    float* spool = (float*)&sW[0][0];    // [16][128], reuse W buffer
    *(float4*)&spool[grp * HID + cagg] = make_float4(p0, p1, p2, p3);
    __syncthreads();
    if (t < HID) {
        float s = 0.f;
#pragma unroll
        for (int i = 0; i < 16; ++i) s += spool[i * HID + t];
        out[(size_t)g * HID + t] = s * (1.f / 64.f) + bias2[t];
    }
}

// ---------- launch ----------
extern "C" void kernel_launch(void* const* d_in, const int* in_sizes, int n_in,
                              void* d_out, int out_size, void* d_ws, size_t ws_size,
                              hipStream_t stream)
{
    (void)in_sizes; (void)n_in; (void)out_size; (void)ws_size;
    const float* fv        = (const float*)d_in[0];
    const float* W_align   = (const float*)d_in[1];
    const float* b_align   = (const float*)d_in[2];
    const float* ln_gamma  = (const float*)d_in[3];
    const float* ln_beta   = (const float*)d_in[4];
    const float* mask_log  = (const float*)d_in[5];
    const float* W1        = (const float*)d_in[6];
    const float* att_src1  = (const float*)d_in[7];
    const float* att_dst1  = (const float*)d_in[8];
    const float* bias1     = (const float*)d_in[9];
    const float* W2        = (const float*)d_in[10];
    const float* att_src2  = (const float*)d_in[11];
    const float* att_dst2  = (const float*)d_in[12];
    const float* bias2     = (const float*)d_in[13];
    const int*   edge_idx  = (const int*)d_in[14];

    float* out = (float*)d_out;                     // [B*HID] emb, then [64] gate
    float* x   = (float*)d_ws;                      // [VTOT*HID]
    float* x1  = x + (size_t)VTOT * HID;            // [VTOT*512]

    k_prep<<<1, EPG, 0, stream>>>(edge_idx);
    k_align<<<VTOT / 16, 256, 0, stream>>>(fv, W_align, b_align, ln_gamma, ln_beta,
                                           mask_log, x, out + (size_t)B_ * HID);
    k_gat1<<<B_ * HEADS, 512, 0, stream>>>(x, W1, att_src1, att_dst1, bias1, x1);
    k_gat2<<<B_, 512, 0, stream>>>(x1, W2, att_src2, att_dst2, bias2, out);
}

// Round 4
// 631.654 us; speedup vs baseline: 1.7667x; 1.7667x over previous
//
#include <hip/hip_runtime.h>
#include <math.h>

#define B_ 1024
#define N_ 64
#define DIN 64
#define HID 128
#define HEADS 4
#define EPG 512                 // edges per graph (448 rand + 64 self loops)
#define VTOT (B_ * N_)          // 65536
#define ETOT (B_ * EPG)         // 524288
#define LN_EPS 1e-5f
#define NEG_SLOPE 0.2f

// CSR of the (shared) edge template: off[65], srcs[512] sorted by dst
__device__ int g_off[65];
__device__ int g_srcs[EPG];

__device__ __forceinline__ float wave_sum(float v) {
#pragma unroll
    for (int o = 32; o > 0; o >>= 1) v += __shfl_xor(v, o);
    return v;
}

// ---------- K0: build template CSR once (1 block, 512 threads) ----------
__global__ void k_prep(const int* __restrict__ edge_index) {
    __shared__ unsigned cnt[64], cur[64];
    __shared__ int soff[65];
    const int t = threadIdx.x;          // one edge per thread
    if (t < 64) cnt[t] = 0u;
    __syncthreads();
    const int sv = edge_index[t];           // graph 0 == template
    const int dv = edge_index[ETOT + t];
    atomicAdd(&cnt[dv], 1u);
    __syncthreads();
    if (t == 0) {
        int a = 0;
        for (int v = 0; v < 64; ++v) { soff[v] = a; cur[v] = (unsigned)a; a += (int)cnt[v]; }
        soff[64] = a;
    }
    __syncthreads();
    const unsigned p = atomicAdd(&cur[dv], 1u);
    g_srcs[p] = sv;
    if (t < 65) g_off[t] = soff[t];
}

// ---------- K1: align Linear(64->128) + LayerNorm + sigmoid gate ----------
// block = 256 threads = 4 waves; each wave handles 4 nodes (16 nodes/block)
__global__ __launch_bounds__(256, 2) void k_align(
    const float* __restrict__ fv, const float* __restrict__ W,
    const float* __restrict__ bias, const float* __restrict__ gamma,
    const float* __restrict__ beta, const float* __restrict__ ml,
    float* __restrict__ x, float* __restrict__ gate_out)
{
    __shared__ float sfv[16][DIN];
    const int t = threadIdx.x;
    const int lane = t & 63, wid = t >> 6;
    const int vbase = blockIdx.x * 16;

    ((float4*)sfv)[t] = ((const float4*)(fv + (size_t)vbase * DIN))[t];
    __syncthreads();

    float acc[4][2];
#pragma unroll
    for (int n = 0; n < 4; ++n) { acc[n][0] = 0.f; acc[n][1] = 0.f; }

    const int nb = wid * 4;
#pragma unroll 8
    for (int k = 0; k < DIN; ++k) {
        const float wlo = W[k * HID + lane];
        const float whi = W[k * HID + 64 + lane];
#pragma unroll
        for (int n = 0; n < 4; ++n) {
            const float f = sfv[nb + n][k];
            acc[n][0] += f * wlo;
            acc[n][1] += f * whi;
        }
    }

    const float blo = bias[lane],  bhi = bias[64 + lane];
    const float glo = gamma[lane], ghi = gamma[64 + lane];
    const float belo = beta[lane], behi = beta[64 + lane];
#pragma unroll
    for (int n = 0; n < 4; ++n) {
        const int v = vbase + nb + n;
        const float a0 = acc[n][0] + blo, a1 = acc[n][1] + bhi;
        const float mu = wave_sum(a0 + a1) * (1.f / HID);
        const float c0v = a0 - mu, c1v = a1 - mu;
        const float var = wave_sum(c0v * c0v + c1v * c1v) * (1.f / HID);
        const float rstd = rsqrtf(var + LN_EPS);
        const float gte = 1.f / (1.f + expf(-ml[v & 63]));
        x[(size_t)v * HID + lane]      = (c0v * rstd * glo + belo) * gte;
        x[(size_t)v * HID + 64 + lane] = (c1v * rstd * ghi + behi) * gte;
    }
    if (blockIdx.x == 0 && t < N_) gate_out[t] = 1.f / (1.f + expf(-ml[t]));
}

// ---------- K2: GAT layer 1 fused: GEMM(128x128 per head) + softmax + agg + ELU ----------
// grid = B*HEADS; block (g,h) with h = bid>>10 so all 4 heads of graph g share an XCD
__global__ __launch_bounds__(512, 2) void k_gat1(
    const float* __restrict__ x, const float* __restrict__ W1,
    const float* __restrict__ att_src1, const float* __restrict__ att_dst1,
    const float* __restrict__ bias1, float* __restrict__ x1)
{
    __shared__ float sx[64][HID];       // x tile, reused in-place as h
    __shared__ float sW[32][HID];       // W1 K-chunk
    __shared__ float s_alpha[EPG];
    __shared__ short s_srcs[EPG];
    __shared__ int   s_off[65];
    __shared__ float sa_src[64], sa_dst[64], s_den[64];

    const int t = threadIdx.x;
    // h slow, g fast: blocks g, g+1024, g+2048, g+3072 -> same XCD (bid%8 == g%8)
    const int g = blockIdx.x & 1023, h = blockIdx.x >> 10;
    const int hbase = h * HID;

    // stage x tile (flat copy) + CSR
    {
        const float4* src4 = (const float4*)(x + (size_t)g * (64 * HID));
        float4* dst4 = (float4*)&sx[0][0];
#pragma unroll
        for (int j = 0; j < 4; ++j) dst4[t + j * 512] = src4[t + j * 512];
        s_srcs[t] = (short)g_srcs[t];
        if (t < 65) s_off[t] = g_off[t];
    }

    // GEMM: h[64][128] = sx @ W1[:, hbase:hbase+128], W staged in 4 chunks of 32 rows
    const int c0 = (t & 31) * 4;
    const int r0 = (t >> 5) * 4;
    float acc[4][4];
#pragma unroll
    for (int i = 0; i < 4; ++i)
#pragma unroll
        for (int j = 0; j < 4; ++j) acc[i][j] = 0.f;

    for (int kc = 0; kc < 4; ++kc) {
        __syncthreads();
        {
            const int i0 = t, i1 = t + 512;
            ((float4*)&sW[0][0])[i0] =
                *(const float4*)&W1[(size_t)(kc * 32 + (i0 >> 5)) * (HEADS * HID) + hbase + (i0 & 31) * 4];
            ((float4*)&sW[0][0])[i1] =
                *(const float4*)&W1[(size_t)(kc * 32 + (i1 >> 5)) * (HEADS * HID) + hbase + (i1 & 31) * 4];
        }
        __syncthreads();
#pragma unroll
        for (int kk = 0; kk < 32; kk += 4) {
            const float4 w0 = *(const float4*)&sW[kk + 0][c0];
            const float4 w1 = *(const float4*)&sW[kk + 1][c0];
            const float4 w2 = *(const float4*)&sW[kk + 2][c0];
            const float4 w3 = *(const float4*)&sW[kk + 3][c0];
            const int k = kc * 32 + kk;
#pragma unroll
            for (int i = 0; i < 4; ++i) {
                const float4 xv = *(const float4*)&sx[r0 + i][k];
                acc[i][0] += xv.x * w0.x + xv.y * w1.x + xv.z * w2.x + xv.w * w3.x;
                acc[i][1] += xv.x * w0.y + xv.y * w1.y + xv.z * w2.y + xv.w * w3.y;
                acc[i][2] += xv.x * w0.z + xv.y * w1.z + xv.z * w2.z + xv.w * w3.z;
                acc[i][3] += xv.x * w0.w + xv.y * w1.w + xv.z * w2.w + xv.w * w3.w;
            }
        }
    }
    __syncthreads();
#pragma unroll
    for (int i = 0; i < 4; ++i)
        *(float4*)&sx[r0 + i][c0] = make_float4(acc[i][0], acc[i][1], acc[i][2], acc[i][3]);
    __syncthreads();

    // per-node attention coefficients (wave per 8 nodes, conflict-free row reads)
    const int lane = t & 63, wid = t >> 6;
    {
        const float as0 = att_src1[hbase + lane], as1 = att_src1[hbase + 64 + lane];
        const float ad0 = att_dst1[hbase + lane], ad1 = att_dst1[hbase + 64 + lane];
#pragma unroll
        for (int i = wid * 8; i < wid * 8 + 8; ++i) {
            const float h0 = sx[i][lane], h1 = sx[i][64 + lane];
            const float vs = wave_sum(h0 * as0 + h1 * as1);
            const float vd = wave_sum(h0 * ad0 + h1 * ad1);
            if (lane == 0) { sa_src[i] = vs; sa_dst[i] = vd; }
        }
    }
    __syncthreads();

    // atomic-free segment softmax: one thread per dst walks its CSR segment
    if (t < 64) {
        const int b = s_off[t], e2 = s_off[t + 1];
        const float sad = sa_dst[t];
        float mx = -1e30f;
        for (int i = b; i < e2; ++i) {
            float sc = sa_src[s_srcs[i]] + sad;
            sc = sc > 0.f ? sc : NEG_SLOPE * sc;
            s_alpha[i] = sc;
            mx = fmaxf(mx, sc);
        }
        float den = 0.f;
        for (int i = b; i < e2; ++i) {
            const float ex = expf(s_alpha[i] - mx);
            s_alpha[i] = ex;
            den += ex;
        }
        s_den[t] = 1.f / (den + 1e-16f);
    }
    __syncthreads();

    // aggregation + bias + ELU + store (16 dst-groups x 32 lanes x float4)
    const int grp = t >> 5, l32 = t & 31;
    const int cagg = l32 * 4;
    const float4 bv = *(const float4*)&bias1[hbase + cagg];
    for (int d = grp; d < 64; d += 16) {
        const int b = s_off[d], e2 = s_off[d + 1];
        const float rden = s_den[d];
        float a0 = 0.f, a1 = 0.f, a2 = 0.f, a3 = 0.f;
        for (int i = b; i < e2; ++i) {
            const float al = s_alpha[i];
            const float4 hv = *(const float4*)&sx[s_srcs[i]][cagg];
            a0 += al * hv.x; a1 += al * hv.y; a2 += al * hv.z; a3 += al * hv.w;
        }
        float4 o;
        o.x = a0 * rden + bv.x; o.y = a1 * rden + bv.y;
        o.z = a2 * rden + bv.z; o.w = a3 * rden + bv.w;
        o.x = o.x > 0.f ? o.x : expm1f(o.x);
        o.y = o.y > 0.f ? o.y : expm1f(o.y);
        o.z = o.z > 0.f ? o.z : expm1f(o.z);
        o.w = o.w > 0.f ? o.w : expm1f(o.w);
        *(float4*)&x1[((size_t)g * 64 + d) * (HEADS * HID) + hbase + cagg] = o;
    }
}

// ---------- K3: GAT layer 2 (512->128, 1 head) + mean pool ----------
// grid = B; block g, 512 threads
__global__ __launch_bounds__(512, 2) void k_gat2(
    const float* __restrict__ x1, const float* __restrict__ W2,
    const float* __restrict__ att_src2, const float* __restrict__ att_dst2,
    const float* __restrict__ bias2, float* __restrict__ out)
{
    __shared__ float schunk[64][HID];   // x1 K-chunk, reused in-place as h
    __shared__ float sW[32][HID];       // W2 K-chunk; later reused as pool buffer
    __shared__ float s_alpha[EPG];
    __shared__ short s_srcs[EPG];
    __shared__ int   s_off[65];
    __shared__ float sa_src[64], sa_dst[64], s_den[64];

    const int t = threadIdx.x;
    const int g = blockIdx.x;

    s_srcs[t] = (short)g_srcs[t];
    if (t < 65) s_off[t] = g_off[t];

    const int c0 = (t & 31) * 4;
    const int r0 = (t >> 5) * 4;
    float acc[4][4];
#pragma unroll
    for (int i = 0; i < 4; ++i)
#pragma unroll
        for (int j = 0; j < 4; ++j) acc[i][j] = 0.f;

    for (int c = 0; c < 4; ++c) {
        __syncthreads();
        {
            const float* src = x1 + (size_t)g * (64 * 512) + c * HID;
#pragma unroll
            for (int j = 0; j < 4; ++j) {
                const int idx = t + j * 512;
                const int r = idx >> 5, c4 = idx & 31;
                *(float4*)&schunk[r][c4 * 4] = *(const float4*)&src[(size_t)r * 512 + c4 * 4];
            }
        }
        for (int kc = 0; kc < 4; ++kc) {
            __syncthreads();
            {
                const int i0 = t, i1 = t + 512;
                ((float4*)&sW[0][0])[i0] =
                    *(const float4*)&W2[(size_t)(c * 128 + kc * 32 + (i0 >> 5)) * HID + (i0 & 31) * 4];
                ((float4*)&sW[0][0])[i1] =
                    *(const float4*)&W2[(size_t)(c * 128 + kc * 32 + (i1 >> 5)) * HID + (i1 & 31) * 4];
            }
            __syncthreads();
#pragma unroll
            for (int kk = 0; kk < 32; kk += 4) {
                const float4 w0 = *(const float4*)&sW[kk + 0][c0];
                const float4 w1 = *(const float4*)&sW[kk + 1][c0];
                const float4 w2 = *(const float4*)&sW[kk + 2][c0];
                const float4 w3 = *(const float4*)&sW[kk + 3][c0];
                const int k = kc * 32 + kk;
#pragma unroll
                for (int i = 0; i < 4; ++i) {
                    const float4 xv = *(const float4*)&schunk[r0 + i][k];
                    acc[i][0] += xv.x * w0.x + xv.y * w1.x + xv.z * w2.x + xv.w * w3.x;
                    acc[i][1] += xv.x * w0.y + xv.y * w1.y + xv.z * w2.y + xv.w * w3.y;
                    acc[i][2] += xv.x * w0.z + xv.y * w1.z + xv.z * w2.z + xv.w * w3.z;
                    acc[i][3] += xv.x * w0.w + xv.y * w1.w + xv.z * w2.w + xv.w * w3.w;
                }
            }
        }
    }
    __syncthreads();
#pragma unroll
    for (int i = 0; i < 4; ++i)
        *(float4*)&schunk[r0 + i][c0] = make_float4(acc[i][0], acc[i][1], acc[i][2], acc[i][3]);
    __syncthreads();

    const int lane = t & 63, wid = t >> 6;
    {
        const float as0 = att_src2[lane], as1 = att_src2[64 + lane];
        const float ad0 = att_dst2[lane], ad1 = att_dst2[64 + lane];
#pragma unroll
        for (int i = wid * 8; i < wid * 8 + 8; ++i) {
            const float h0 = schunk[i][lane], h1 = schunk[i][64 + lane];
            const float vs = wave_sum(h0 * as0 + h1 * as1);
            const float vd = wave_sum(h0 * ad0 + h1 * ad1);
            if (lane == 0) { sa_src[i] = vs; sa_dst[i] = vd; }
        }
    }
    __syncthreads();

    if (t < 64) {
        const int b = s_off[t], e2 = s_off[t + 1];
        const float sad = sa_dst[t];
        float mx = -1e30f;
        for (int i = b; i < e2; ++i) {
            float sc = sa_src[s_srcs[i]] + sad;
            sc = sc > 0.f ? sc : NEG_SLOPE * sc;
            s_alpha[i] = sc;
            mx = fmaxf(mx, sc);
        }
        float den = 0.f;
        for (int i = b; i < e2; ++i) {
            const float ex = expf(s_alpha[i] - mx);
            s_alpha[i] = ex;
            den += ex;
        }
        s_den[t] = 1.f / (den + 1e-16f);
    }
    __syncthreads();

    // aggregation + mean pool (bias2 added once after pooling; biases commute with mean)
    const int grp = t >> 5, l32 = t & 31;
    const int cagg = l32 * 4;
    float p0 = 0.f, p1 = 0.f, p2 = 0.f, p3 = 0.f;
    for (int d = grp; d < 64; d += 16) {
        const int b = s_off[d], e2 = s_off[d + 1];
        const float rden = s_den[d];
        float a0 = 0.f, a1 = 0.f, a2 = 0.f, a3 = 0.f;
        for (int i = b; i < e2; ++i) {
            const float al = s_alpha[i];
            const float4 hv = *(const float4*)&schunk[s_srcs[i]][cagg];
            a0 += al * hv.x; a1 += al * hv.y; a2 += al * hv.z; a3 += al * hv.w;
        }
        p0 += a0 * rden; p1 += a1 * rden; p2 += a2 * rden; p3 += a3 * rden;
    }
    float* spool = (float*)&sW[0][0];    // [16][128], reuse W buffer
    *(float4*)&spool[grp * HID + cagg] = make_float4(p0, p1, p2, p3);
    __syncthreads();
    if (t < HID) {
        float s = 0.f;
#pragma unroll
        for (int i = 0; i < 16; ++i) s += spool[i * HID + t];
        out[(size_t)g * HID + t] = s * (1.f / 64.f) + bias2[t];
    }
}

// ---------- launch ----------
extern "C" void kernel_launch(void* const* d_in, const int* in_sizes, int n_in,
                              void* d_out, int out_size, void* d_ws, size_t ws_size,
                              hipStream_t stream)
{
    (void)in_sizes; (void)n_in; (void)out_size; (void)ws_size;
    const float* fv        = (const float*)d_in[0];
    const float* W_align   = (const float*)d_in[1];
    const float* b_align   = (const float*)d_in[2];
    const float* ln_gamma  = (const float*)d_in[3];
    const float* ln_beta   = (const float*)d_in[4];
    const float* mask_log  = (const float*)d_in[5];
    const float* W1        = (const float*)d_in[6];
    const float* att_src1  = (const float*)d_in[7];
    const float* att_dst1  = (const float*)d_in[8];
    const float* bias1     = (const float*)d_in[9];
    const float* W2        = (const float*)d_in[10];
    const float* att_src2  = (const float*)d_in[11];
    const float* att_dst2  = (const float*)d_in[12];
    const float* bias2     = (const float*)d_in[13];
    const int*   edge_idx  = (const int*)d_in[14];

    float* out = (float*)d_out;                     // [B*HID] emb, then [64] gate
    float* x   = (float*)d_ws;                      // [VTOT*HID]
    float* x1  = x + (size_t)VTOT * HID;            // [VTOT*512]

    k_prep<<<1, EPG, 0, stream>>>(edge_idx);
    k_align<<<VTOT / 16, 256, 0, stream>>>(fv, W_align, b_align, ln_gamma, ln_beta,
                                           mask_log, x, out + (size_t)B_ * HID);
    k_gat1<<<B_ * HEADS, 512, 0, stream>>>(x, W1, att_src1, att_dst1, bias1, x1);
    k_gat2<<<B_, 512, 0, stream>>>(x1, W2, att_src2, att_dst2, bias2, out);
}

// Round 8
// 348.737 us; speedup vs baseline: 3.2000x; 1.8113x over previous
//
#include <hip/hip_runtime.h>
#include <math.h>

#define B_ 1024
#define N_ 64
#define DIN 64
#define HID 128
#define HEADS 4
#define EPG 512                 // edges per graph (448 rand + 64 self loops)
#define ETOT (B_ * EPG)
#define LN_EPS 1e-5f
#define NEG_SLOPE 0.2f
#define NT 512

typedef _Float16 f16;
typedef _Float16 f16x8 __attribute__((ext_vector_type(8)));
typedef _Float16 f16x4 __attribute__((ext_vector_type(4)));
typedef float f32x4 __attribute__((ext_vector_type(4)));

// CSR of the (shared) edge template
__device__ int g_off[65];
__device__ int g_srcs[EPG];

__device__ __forceinline__ float wave_sum(float v) {
#pragma unroll
    for (int o = 32; o > 0; o >>= 1) v += __shfl_xor(v, o);
    return v;
}

// XOR swizzle: spread 16B granules of a row across banks (row-based involution)
#define SWZ(row, byteoff) ((byteoff) ^ (((row) & 7) << 4))

// ---- LDS layout (bytes) ----
#define OFF_XF16   0        // x_f16 [64][128] f16 swizzled, rowstride 256 (16KB)
#define OFF_BUFA   16384    // 32KB: W_align f32 | WT f16 [128][128] swz | h f32 [64][128] linear
#define OFF_X1     49152    // x1_f16 [64][512] f16 swz rowstride 1024 (64KB); align: fv f32; end: pool f32[16][128]
#define OFF_ALPHA  114688   // f32[512]
#define OFF_SRCS   116736   // short[512]
#define OFF_OFFS   117760   // int[65] (+pad)
#define OFF_SASRC  118032   // f32[64]
#define OFF_SADST  118288   // f32[64]
#define OFF_SDEN   118544   // f32[64]
#define LDS_BYTES  118800

// ---------- K0: build template CSR once ----------
__global__ void k_prep(const int* __restrict__ edge_index) {
    __shared__ unsigned cnt[64], cur[64];
    __shared__ int soff[65];
    const int t = threadIdx.x;
    if (t < 64) cnt[t] = 0u;
    __syncthreads();
    const int sv = edge_index[t];           // graph 0 == template
    const int dv = edge_index[ETOT + t];
    atomicAdd(&cnt[dv], 1u);
    __syncthreads();
    if (t == 0) {
        int a = 0;
        for (int v = 0; v < 64; ++v) { soff[v] = a; cur[v] = (unsigned)a; a += (int)cnt[v]; }
        soff[64] = a;
    }
    __syncthreads();
    const unsigned p = atomicAdd(&cur[dv], 1u);
    g_srcs[p] = sv;
    if (t < 65) g_off[t] = soff[t];
}

// ---------- K0b: convert weights to f16, transposed to n-major ----------
// W1T[h][n][k] (k=128 contiguous), W2T[n][k] (k=512 contiguous)
__global__ __launch_bounds__(512) void k_prepw(
    const float* __restrict__ W1, const float* __restrict__ W2,
    f16* __restrict__ W1T, f16* __restrict__ W2T)
{
    const int tid = blockIdx.x * 512 + threadIdx.x;   // grid 256 -> 131072
    if (tid < 65536) {
        const int h = tid >> 14, n = (tid >> 7) & 127, k = tid & 127;
        W1T[tid] = (f16)W1[(size_t)k * 512 + h * 128 + n];
    } else {
        const int i = tid - 65536;
        const int n = i >> 9, k = i & 511;
        W2T[i] = (f16)W2[(size_t)k * 128 + n];
    }
}

// stage a [128 rows][256B] f16 tile from global into BUFA, swizzled
__device__ __forceinline__ void stage_wt(unsigned char* smem,
                                         const unsigned char* src, int srcRowBytes, int t)
{
#pragma unroll
    for (int j = 0; j < 4; ++j) {
        const int gi = t + j * 512;          // 2048 granules of 16B
        const int row = gi >> 4, c16 = gi & 15;
        *(float4*)(smem + OFF_BUFA + row * 256 + SWZ(row, c16 * 16)) =
            *(const float4*)(src + (size_t)row * srcRowBytes + c16 * 16);
    }
}

// MFMA: wave w owns mt=w&3, nt = (w>>2)*4 + 0..3; A from (abase,arow) swizzled, B from BUFA
__device__ __forceinline__ void mma_tiles(const unsigned char* smem, int abase, int arow,
                                          int kstep0, int ksteps, int t, f32x4 acc[4])
{
    const int lane = t & 63, w = t >> 6;
    const int arownum = (w & 3) * 16 + (lane & 15);
    const int brow0 = (w >> 2) * 64 + (lane & 15);
    const int kb = (lane >> 4) * 16;    // byte offset of this lane's 8-f16 group within 64B k-block
    for (int ks = kstep0; ks < kstep0 + ksteps; ++ks) {
        const f16x8 a = *(const f16x8*)(smem + abase + (size_t)arownum * arow +
                                        SWZ(arownum, ks * 64 + kb));
#pragma unroll
        for (int i = 0; i < 4; ++i) {
            const int br = brow0 + i * 16;
            const f16x8 b = *(const f16x8*)(smem + OFF_BUFA + br * 256 +
                                            SWZ(br, (ks - kstep0) * 64 + kb));
            acc[i] = __builtin_amdgcn_mfma_f32_16x16x32_f16(a, b, acc[i], 0, 0, 0);
        }
    }
}

// write C (f32x4 per tile, C layout col=lane&15 row=(lane>>4)*4+reg) into BUFA f32[64][128]
__device__ __forceinline__ void write_c(unsigned char* smem, int t, const f32x4 acc[4])
{
    const int lane = t & 63, w = t >> 6;
    float* hb = (float*)(smem + OFF_BUFA);
    const int r0 = (w & 3) * 16 + (lane >> 4) * 4;
#pragma unroll
    for (int i = 0; i < 4; ++i) {
        const int col = (w >> 2) * 64 + i * 16 + (lane & 15);
#pragma unroll
        for (int r = 0; r < 4; ++r) hb[(size_t)(r0 + r) * HID + col] = acc[i][r];
    }
}

// ---------- fused: align+LN+gate -> GAT1(4 heads)+ELU -> GAT2 -> mean pool ----------
__global__ __launch_bounds__(NT, 1) void k_fused(
    const float* __restrict__ fv, const float* __restrict__ Wal,
    const float* __restrict__ bal, const float* __restrict__ gam,
    const float* __restrict__ bet, const float* __restrict__ ml,
    const f16* __restrict__ W1T, const float* __restrict__ as1,
    const float* __restrict__ ad1, const float* __restrict__ b1,
    const f16* __restrict__ W2T, const float* __restrict__ as2,
    const float* __restrict__ ad2, const float* __restrict__ b2,
    float* __restrict__ out)
{
    __shared__ __align__(16) unsigned char smem[LDS_BYTES];
    const int t = threadIdx.x, lane = t & 63, w = t >> 6;
    const int g = blockIdx.x;

    float* bufaF = (float*)(smem + OFF_BUFA);       // align: W_align; later h (f32)
    float* fvs   = (float*)(smem + OFF_X1);         // align: fv tile
    float* alpha = (float*)(smem + OFF_ALPHA);
    short* srcs  = (short*)(smem + OFF_SRCS);
    int*   offs  = (int*)(smem + OFF_OFFS);
    float* sasrc = (float*)(smem + OFF_SASRC);
    float* sadst = (float*)(smem + OFF_SADST);
    float* sden  = (float*)(smem + OFF_SDEN);

    // ---- stage CSR + fv + W_align
    srcs[t] = (short)g_srcs[t];
    if (t < 65) offs[t] = g_off[t];
    {
        const float4* s4 = (const float4*)(fv + (size_t)g * 64 * DIN);
        float4* d4 = (float4*)fvs;
        d4[t] = s4[t]; d4[t + 512] = s4[t + 512];           // 16KB fv
        const float4* w4 = (const float4*)Wal;
        float4* b4 = (float4*)bufaF;
#pragma unroll
        for (int j = 0; j < 4; ++j) b4[t + j * 512] = w4[t + j * 512];   // 32KB W_align
    }
    __syncthreads();

    // ---- align + LN + gate -> x_f16 (swizzled)
    {
        const float blo = bal[lane], bhi = bal[64 + lane];
        const float glo = gam[lane], ghi = gam[64 + lane];
        const float belo = bet[lane], behi = bet[64 + lane];
        for (int n = w * 8; n < w * 8 + 8; ++n) {
            float a0 = 0.f, a1 = 0.f;
#pragma unroll 8
            for (int k = 0; k < DIN; ++k) {
                const float f = fvs[n * DIN + k];
                a0 += f * bufaF[k * HID + lane];
                a1 += f * bufaF[k * HID + 64 + lane];
            }
            a0 += blo; a1 += bhi;
            const float mu = wave_sum(a0 + a1) * (1.f / HID);
            const float c0 = a0 - mu, c1 = a1 - mu;
            const float var = wave_sum(c0 * c0 + c1 * c1) * (1.f / HID);
            const float rs = rsqrtf(var + LN_EPS);
            const float gt = 1.f / (1.f + expf(-ml[n]));
            *(f16*)(smem + OFF_XF16 + n * 256 + SWZ(n, lane * 2)) = (f16)((c0 * rs * glo + belo) * gt);
            *(f16*)(smem + OFF_XF16 + n * 256 + SWZ(n, 128 + lane * 2)) = (f16)((c1 * rs * ghi + behi) * gt);
        }
    }
    if (g == 0 && t < 64) out[(size_t)B_ * HID + t] = 1.f / (1.f + expf(-ml[t]));
    __syncthreads();

    // ---- GAT layer 1, per head ----
    for (int h = 0; h < HEADS; ++h) {
        stage_wt(smem, (const unsigned char*)(W1T + (size_t)h * 128 * 128), 256, t);
        __syncthreads();
        f32x4 acc[4];
#pragma unroll
        for (int i = 0; i < 4; ++i) acc[i] = (f32x4){0.f, 0.f, 0.f, 0.f};
        mma_tiles(smem, OFF_XF16, 256, 0, 4, t, acc);
        __syncthreads();                 // all B reads done before overwriting BUFA
        write_c(smem, t, acc);
        __syncthreads();

        // attention coefficients: wave per 8 nodes
        {
            const float s0 = as1[h * HID + lane], s1v = as1[h * HID + 64 + lane];
            const float d0 = ad1[h * HID + lane], d1v = ad1[h * HID + 64 + lane];
            for (int i = w * 8; i < w * 8 + 8; ++i) {
                const float h0 = bufaF[i * HID + lane], h1v = bufaF[i * HID + 64 + lane];
                const float vs = wave_sum(h0 * s0 + h1v * s1v);
                const float vd = wave_sum(h0 * d0 + h1v * d1v);
                if (lane == 0) { sasrc[i] = vs; sadst[i] = vd; }
            }
        }
        __syncthreads();

        // segment softmax: 8 lanes per dst, all 512 threads active
        {
            const int g8 = t >> 3, sl = t & 7;
            const int b = offs[g8], e = offs[g8 + 1];
            const float sad = sadst[g8];
            float mx = -1e30f;
            for (int i = b + sl; i < e; i += 8) {
                float sc = sasrc[srcs[i]] + sad;
                sc = sc > 0.f ? sc : NEG_SLOPE * sc;
                alpha[i] = sc;
                mx = fmaxf(mx, sc);
            }
#pragma unroll
            for (int o = 1; o < 8; o <<= 1) mx = fmaxf(mx, __shfl_xor(mx, o));
            float den = 0.f;
            for (int i = b + sl; i < e; i += 8) {
                const float ex = expf(alpha[i] - mx);
                alpha[i] = ex;
                den += ex;
            }
#pragma unroll
            for (int o = 1; o < 8; o <<= 1) den += __shfl_xor(den, o);
            if (sl == 0) sden[g8] = 1.f / (den + 1e-16f);
        }
        __syncthreads();

        // aggregate + bias + ELU -> x1_f16 (swizzled)
        {
            const int grp = t >> 5, l32 = t & 31, c = l32 * 4;
            const float4 bv = *(const float4*)&b1[h * HID + c];
            for (int d = grp; d < 64; d += 16) {
                const int b = offs[d], e = offs[d + 1];
                const float rd = sden[d];
                float a0 = 0.f, a1 = 0.f, a2 = 0.f, a3 = 0.f;
                for (int i = b; i < e; ++i) {
                    const float al = alpha[i];
                    const float4 hv = *(const float4*)&bufaF[(size_t)srcs[i] * HID + c];
                    a0 += al * hv.x; a1 += al * hv.y; a2 += al * hv.z; a3 += al * hv.w;
                }
                float o0 = a0 * rd + bv.x, o1 = a1 * rd + bv.y;
                float o2 = a2 * rd + bv.z, o3 = a3 * rd + bv.w;
                o0 = o0 > 0.f ? o0 : expm1f(o0);
                o1 = o1 > 0.f ? o1 : expm1f(o1);
                o2 = o2 > 0.f ? o2 : expm1f(o2);
                o3 = o3 > 0.f ? o3 : expm1f(o3);
                f16x4 p; p.x = (f16)o0; p.y = (f16)o1; p.z = (f16)o2; p.w = (f16)o3;
                *(f16x4*)(smem + OFF_X1 + d * 1024 + SWZ(d, h * 256 + c * 2)) = p;
            }
        }
        __syncthreads();                 // x1 slice done; BUFA free for next head
    }

    // ---- GAT layer 2: h2[64][128] = x1[64][512] @ W2, K in 4 chunks ----
    f32x4 acc2[4];
#pragma unroll
    for (int i = 0; i < 4; ++i) acc2[i] = (f32x4){0.f, 0.f, 0.f, 0.f};
    for (int kc = 0; kc < 4; ++kc) {
        stage_wt(smem, (const unsigned char*)W2T + (size_t)kc * 256, 1024, t);
        __syncthreads();
        mma_tiles(smem, OFF_X1, 1024, kc * 4, 4, t, acc2);
        __syncthreads();
    }
    write_c(smem, t, acc2);
    __syncthreads();

    // attention 2 (single head)
    {
        const float s0 = as2[lane], s1v = as2[64 + lane];
        const float d0 = ad2[lane], d1v = ad2[64 + lane];
        for (int i = w * 8; i < w * 8 + 8; ++i) {
            const float h0 = bufaF[i * HID + lane], h1v = bufaF[i * HID + 64 + lane];
            const float vs = wave_sum(h0 * s0 + h1v * s1v);
            const float vd = wave_sum(h0 * d0 + h1v * d1v);
            if (lane == 0) { sasrc[i] = vs; sadst[i] = vd; }
        }
    }
    __syncthreads();
    {
        const int g8 = t >> 3, sl = t & 7;
        const int b = offs[g8], e = offs[g8 + 1];
        const float sad = sadst[g8];
        float mx = -1e30f;
        for (int i = b + sl; i < e; i += 8) {
            float sc = sasrc[srcs[i]] + sad;
            sc = sc > 0.f ? sc : NEG_SLOPE * sc;
            alpha[i] = sc;
            mx = fmaxf(mx, sc);
        }
#pragma unroll
        for (int o = 1; o < 8; o <<= 1) mx = fmaxf(mx, __shfl_xor(mx, o));
        float den = 0.f;
        for (int i = b + sl; i < e; i += 8) {
            const float ex = expf(alpha[i] - mx);
            alpha[i] = ex;
            den += ex;
        }
#pragma unroll
        for (int o = 1; o < 8; o <<= 1) den += __shfl_xor(den, o);
        if (sl == 0) sden[g8] = 1.f / (den + 1e-16f);
    }
    __syncthreads();

    // aggregate + mean pool (bias2 added after pooling; commutes with mean)
    {
        const int grp = t >> 5, l32 = t & 31, c = l32 * 4;
        float p0 = 0.f, p1 = 0.f, p2 = 0.f, p3 = 0.f;
        for (int d = grp; d < 64; d += 16) {
            const int b = offs[d], e = offs[d + 1];
            const float rd = sden[d];
            float a0 = 0.f, a1 = 0.f, a2 = 0.f, a3 = 0.f;
            for (int i = b; i < e; ++i) {
                const float al = alpha[i];
                const float4 hv = *(const float4*)&bufaF[(size_t)srcs[i] * HID + c];
                a0 += al * hv.x; a1 += al * hv.y; a2 += al * hv.z; a3 += al * hv.w;
            }
            p0 += a0 * rd; p1 += a1 * rd; p2 += a2 * rd; p3 += a3 * rd;
        }
        float* pool = (float*)(smem + OFF_X1);      // x1 region free now
        *(float4*)&pool[(size_t)grp * HID + c] = make_float4(p0, p1, p2, p3);
    }
    __syncthreads();
    if (t < HID) {
        const float* pool = (const float*)(smem + OFF_X1);
        float s = 0.f;
#pragma unroll
        for (int i = 0; i < 16; ++i) s += pool[(size_t)i * HID + t];
        out[(size_t)g * HID + t] = s * (1.f / 64.f) + b2[t];
    }
}

// ---------- launch ----------
extern "C" void kernel_launch(void* const* d_in, const int* in_sizes, int n_in,
                              void* d_out, int out_size, void* d_ws, size_t ws_size,
                              hipStream_t stream)
{
    (void)in_sizes; (void)n_in; (void)out_size; (void)ws_size;
    const float* fv        = (const float*)d_in[0];
    const float* W_align   = (const float*)d_in[1];
    const float* b_align   = (const float*)d_in[2];
    const float* ln_gamma  = (const float*)d_in[3];
    const float* ln_beta   = (const float*)d_in[4];
    const float* mask_log  = (const float*)d_in[5];
    const float* W1        = (const float*)d_in[6];
    const float* att_src1  = (const float*)d_in[7];
    const float* att_dst1  = (const float*)d_in[8];
    const float* bias1     = (const float*)d_in[9];
    const float* W2        = (const float*)d_in[10];
    const float* att_src2  = (const float*)d_in[11];
    const float* att_dst2  = (const float*)d_in[12];
    const float* bias2     = (const float*)d_in[13];
    const int*   edge_idx  = (const int*)d_in[14];

    float* out = (float*)d_out;                 // [B*HID] emb, then [64] gate
    f16* W1T = (f16*)d_ws;                      // [4][128][128]
    f16* W2T = W1T + 65536;                     // [128][512]

    k_prep<<<1, EPG, 0, stream>>>(edge_idx);
    k_prepw<<<256, 512, 0, stream>>>(W1, W2, W1T, W2T);
    k_fused<<<B_, NT, 0, stream>>>(fv, W_align, b_align, ln_gamma, ln_beta, mask_log,
                                   W1T, att_src1, att_dst1, bias1,
                                   W2T, att_src2, att_dst2, bias2, out);
}

// Round 14
// 302.709 us; speedup vs baseline: 3.6866x; 1.1521x over previous
//
#include <hip/hip_runtime.h>
#include <math.h>

#define B_ 1024
#define N_ 64
#define DIN 64
#define HID 128
#define HEADS 4
#define EPG 512                 // edges per graph (448 rand + 64 self loops)
#define ETOT (B_ * EPG)
#define LN_EPS 1e-5f
#define NEG_SLOPE 0.2f
#define NT 512

typedef _Float16 f16;
typedef _Float16 f16x8 __attribute__((ext_vector_type(8)));
typedef _Float16 f16x4 __attribute__((ext_vector_type(4)));
typedef float f32x4 __attribute__((ext_vector_type(4)));

// CSR of the (shared) edge template
__device__ int g_off[65];
__device__ int g_srcs[EPG];

__device__ __forceinline__ float wave_sum(float v) {
#pragma unroll
    for (int o = 32; o > 0; o >>= 1) v += __shfl_xor(v, o);
    return v;
}

// XOR swizzle: spread 16B granules of a row across banks (row-based involution)
#define SWZ(row, byteoff) ((byteoff) ^ (((row) & 7) << 4))

// ---- LDS layout (bytes); total 69648 -> 2 blocks/CU (139.3KB of 160KB) ----
#define OFF_XF16   0        // x_f16 [64][128] f16 swz, rowstride 256B (16KB)
#define OFF_H32    16384    // h f32 [64][128] linear (32KB); align: W_align f32 stage
#define OFF_X1H    49152    // x1_h f16 [64][128] swz (16KB); align: fv f32 [64][64]; tail: pool f32[16][128]
#define OFF_ALPHA  65536    // f32[512]
#define OFF_SRCS   67584    // short[512]
#define OFF_OFFS   68608    // int[66]
#define OFF_SASRC  68880    // f32[64]
#define OFF_SADST  69136    // f32[64]
#define OFF_SDEN   69392    // f32[64]
#define LDS_BYTES  69648

// ---------- K0: build template CSR once ----------
__global__ void k_prep(const int* __restrict__ edge_index) {
    __shared__ unsigned cnt[64], cur[64];
    __shared__ int soff[65];
    const int t = threadIdx.x;
    if (t < 64) cnt[t] = 0u;
    __syncthreads();
    const int sv = edge_index[t];           // graph 0 == template
    const int dv = edge_index[ETOT + t];
    atomicAdd(&cnt[dv], 1u);
    __syncthreads();
    if (t == 0) {
        int a = 0;
        for (int v = 0; v < 64; ++v) { soff[v] = a; cur[v] = (unsigned)a; a += (int)cnt[v]; }
        soff[64] = a;
    }
    __syncthreads();
    const unsigned p = atomicAdd(&cur[dv], 1u);
    g_srcs[p] = sv;
    if (t < 65) g_off[t] = soff[t];
}

// ---------- K0b: convert weights to f16, transposed to n-major ----------
// W1T[h][n][k] (k=128 contiguous), W2T[n][k] (k=512 contiguous)
__global__ __launch_bounds__(512) void k_prepw(
    const float* __restrict__ W1, const float* __restrict__ W2,
    f16* __restrict__ W1T, f16* __restrict__ W2T)
{
    const int tid = blockIdx.x * 512 + threadIdx.x;   // grid 256 -> 131072
    if (tid < 65536) {
        const int h = tid >> 14, n = (tid >> 7) & 127, k = tid & 127;
        W1T[tid] = (f16)W1[(size_t)k * 512 + h * 128 + n];
    } else {
        const int i = tid - 65536;
        const int n = i >> 9, k = i & 511;
        W2T[i] = (f16)W2[(size_t)k * 128 + n];
    }
}

// MFMA with A from swizzled LDS (rowstride 256B), B n-major from GLOBAL (L2-resident).
// wave w: A rows (w&3)*16..+16, B cols (w>>2)*64..+64; K=128 in 4 steps.
__device__ __forceinline__ void mma_g(const unsigned char* smem, int abase,
                                      const f16* __restrict__ B, int bstride,
                                      int t, f32x4 acc[4])
{
    const int lane = t & 63, w = t >> 6;
    const int am = (w & 3) * 16 + (lane & 15);
    const int bn = (w >> 2) * 64 + (lane & 15);
    const int ke = (lane >> 4) * 8;          // element offset in k
#pragma unroll
    for (int ks = 0; ks < 4; ++ks) {
        const f16x8 a = *(const f16x8*)(smem + abase + am * 256 + SWZ(am, ks * 64 + ke * 2));
#pragma unroll
        for (int i = 0; i < 4; ++i) {
            const f16x8 b = *(const f16x8*)(B + (size_t)(bn + i * 16) * bstride + ks * 32 + ke);
            acc[i] = __builtin_amdgcn_mfma_f32_16x16x32_f16(a, b, acc[i], 0, 0, 0);
        }
    }
}

// write C (f32x4 per tile, layout col=lane&15 row=(lane>>4)*4+reg) into H32 f32[64][128]
__device__ __forceinline__ void write_c(unsigned char* smem, int t, const f32x4 acc[4])
{
    const int lane = t & 63, w = t >> 6;
    float* hb = (float*)(smem + OFF_H32);
    const int r0 = (w & 3) * 16 + (lane >> 4) * 4;
#pragma unroll
    for (int i = 0; i < 4; ++i) {
        const int col = (w >> 2) * 64 + i * 16 + (lane & 15);
#pragma unroll
        for (int r = 0; r < 4; ++r) hb[(size_t)(r0 + r) * HID + col] = acc[i][r];
    }
}

// ---------- fused: align+LN+gate -> GAT1(4 heads)+ELU -> GAT2 (per-head acc) -> pool ----------
__global__ __launch_bounds__(NT, 2) void k_fused(
    const float* __restrict__ fv, const float* __restrict__ Wal,
    const float* __restrict__ bal, const float* __restrict__ gam,
    const float* __restrict__ bet, const float* __restrict__ ml,
    const f16* __restrict__ W1T, const float* __restrict__ as1,
    const float* __restrict__ ad1, const float* __restrict__ b1,
    const f16* __restrict__ W2T, const float* __restrict__ as2,
    const float* __restrict__ ad2, const float* __restrict__ b2,
    float* __restrict__ out)
{
    __shared__ __align__(16) unsigned char smem[LDS_BYTES];
    const int t = threadIdx.x, lane = t & 63, w = t >> 6;
    const int g = blockIdx.x;

    float* hF    = (float*)(smem + OFF_H32);
    float* alpha = (float*)(smem + OFF_ALPHA);
    short* srcs  = (short*)(smem + OFF_SRCS);
    int*   offs  = (int*)(smem + OFF_OFFS);
    float* sasrc = (float*)(smem + OFF_SASRC);
    float* sadst = (float*)(smem + OFF_SADST);
    float* sden  = (float*)(smem + OFF_SDEN);

    // ---- stage CSR + fv (f32 -> X1H) + W_align (f32 -> H32)
    srcs[t] = (short)g_srcs[t];
    if (t < 65) offs[t] = g_off[t];
    {
        const float4* s4 = (const float4*)(fv + (size_t)g * 64 * DIN);
        float4* d4 = (float4*)(smem + OFF_X1H);
        d4[t] = s4[t]; d4[t + 512] = s4[t + 512];           // 16KB fv
        const float4* w4 = (const float4*)Wal;
        float4* b4 = (float4*)hF;
#pragma unroll
        for (int j = 0; j < 4; ++j) b4[t + j * 512] = w4[t + j * 512];   // 32KB W_align
    }
    __syncthreads();

    // ---- align + LN + gate -> x_f16 (swizzled); k-outer, W read once per k
    {
        const float* fvs = (const float*)(smem + OFF_X1H);  // [64][64]
        const int nb = w * 8;
        float acc0[8], acc1[8];
#pragma unroll
        for (int n = 0; n < 8; ++n) { acc0[n] = 0.f; acc1[n] = 0.f; }
        for (int k4 = 0; k4 < 16; ++k4) {
            const int k = k4 * 4;
            const float wl0 = hF[(k + 0) * HID + lane], wh0 = hF[(k + 0) * HID + 64 + lane];
            const float wl1 = hF[(k + 1) * HID + lane], wh1 = hF[(k + 1) * HID + 64 + lane];
            const float wl2 = hF[(k + 2) * HID + lane], wh2 = hF[(k + 2) * HID + 64 + lane];
            const float wl3 = hF[(k + 3) * HID + lane], wh3 = hF[(k + 3) * HID + 64 + lane];
#pragma unroll
            for (int n = 0; n < 8; ++n) {
                const float4 f = *(const float4*)&fvs[(nb + n) * DIN + k];
                acc0[n] += f.x * wl0 + f.y * wl1 + f.z * wl2 + f.w * wl3;
                acc1[n] += f.x * wh0 + f.y * wh1 + f.z * wh2 + f.w * wh3;
            }
        }
        const float blo = bal[lane],  bhi = bal[64 + lane];
        const float glo = gam[lane],  ghi = gam[64 + lane];
        const float belo = bet[lane], behi = bet[64 + lane];
#pragma unroll
        for (int n = 0; n < 8; ++n) {
            const int node = nb + n;
            const float a0 = acc0[n] + blo, a1 = acc1[n] + bhi;
            const float mu = wave_sum(a0 + a1) * (1.f / HID);
            const float c0 = a0 - mu, c1 = a1 - mu;
            const float var = wave_sum(c0 * c0 + c1 * c1) * (1.f / HID);
            const float rs = rsqrtf(var + LN_EPS);
            const float gt = 1.f / (1.f + __expf(-ml[node]));
            *(f16*)(smem + OFF_XF16 + node * 256 + SWZ(node, lane * 2)) =
                (f16)((c0 * rs * glo + belo) * gt);
            *(f16*)(smem + OFF_XF16 + node * 256 + SWZ(node, 128 + lane * 2)) =
                (f16)((c1 * rs * ghi + behi) * gt);
        }
    }
    if (g == 0 && t < 64) out[(size_t)B_ * HID + t] = 1.f / (1.f + __expf(-ml[t]));
    __syncthreads();

    // ---- head loop: GAT1 head h -> x1_h; acc2 += x1_h @ W2T[:, h*128:+128]
    f32x4 acc2[4];
#pragma unroll
    for (int i = 0; i < 4; ++i) acc2[i] = (f32x4){0.f, 0.f, 0.f, 0.f};

    for (int h = 0; h < HEADS; ++h) {
        // GEMM1 (A=x_f16 LDS, B=W1T global) -> h f32 in H32
        f32x4 acc[4];
#pragma unroll
        for (int i = 0; i < 4; ++i) acc[i] = (f32x4){0.f, 0.f, 0.f, 0.f};
        mma_g(smem, OFF_XF16, W1T + (size_t)h * HID * HID, HID, t, acc);
        write_c(smem, t, acc);           // H32 last read pre-barrier-I of prev head
        __syncthreads();                 // C

        // attention coefficients: wave per 8 nodes
        {
            const float s0 = as1[h * HID + lane], s1v = as1[h * HID + 64 + lane];
            const float d0 = ad1[h * HID + lane], d1v = ad1[h * HID + 64 + lane];
            for (int i = w * 8; i < w * 8 + 8; ++i) {
                const float h0 = hF[i * HID + lane], h1v = hF[i * HID + 64 + lane];
                const float vs = wave_sum(h0 * s0 + h1v * s1v);
                const float vd = wave_sum(h0 * d0 + h1v * d1v);
                if (lane == 0) { sasrc[i] = vs; sadst[i] = vd; }
            }
        }
        __syncthreads();                 // E

        // segment softmax: 8 lanes per dst
        {
            const int g8 = t >> 3, sl = t & 7;
            const int b = offs[g8], e = offs[g8 + 1];
            const float sad = sadst[g8];
            float mx = -1e30f;
            for (int i = b + sl; i < e; i += 8) {
                float sc = sasrc[srcs[i]] + sad;
                sc = sc > 0.f ? sc : NEG_SLOPE * sc;
                alpha[i] = sc;
                mx = fmaxf(mx, sc);
            }
#pragma unroll
            for (int o = 1; o < 8; o <<= 1) mx = fmaxf(mx, __shfl_xor(mx, o));
            float den = 0.f;
            for (int i = b + sl; i < e; i += 8) {
                const float ex = __expf(alpha[i] - mx);
                alpha[i] = ex;
                den += ex;
            }
#pragma unroll
            for (int o = 1; o < 8; o <<= 1) den += __shfl_xor(den, o);
            if (sl == 0) sden[g8] = 1.f / (den + 1e-16f);
        }
        __syncthreads();                 // G

        // aggregate + bias + ELU -> x1_h f16 swz (X1H)
        {
            const int grp = t >> 5, l32 = t & 31, c = l32 * 4;
            const float4 bv = *(const float4*)&b1[h * HID + c];
            for (int d = grp; d < 64; d += 16) {
                const int b = offs[d], e = offs[d + 1];
                const float rd = sden[d];
                float a0 = 0.f, a1 = 0.f, a2 = 0.f, a3 = 0.f;
                for (int i = b; i < e; ++i) {
                    const float al = alpha[i];
                    const float4 hv = *(const float4*)&hF[(size_t)srcs[i] * HID + c];
                    a0 += al * hv.x; a1 += al * hv.y; a2 += al * hv.z; a3 += al * hv.w;
                }
                float o0 = a0 * rd + bv.x, o1 = a1 * rd + bv.y;
                float o2 = a2 * rd + bv.z, o3 = a3 * rd + bv.w;
                o0 = o0 > 0.f ? o0 : expm1f(o0);
                o1 = o1 > 0.f ? o1 : expm1f(o1);
                o2 = o2 > 0.f ? o2 : expm1f(o2);
                o3 = o3 > 0.f ? o3 : expm1f(o3);
                f16x4 p; p.x = (f16)o0; p.y = (f16)o1; p.z = (f16)o2; p.w = (f16)o3;
                *(f16x4*)(smem + OFF_X1H + d * 256 + SWZ(d, c * 2)) = p;
            }
        }
        __syncthreads();                 // I

        // GEMM2 chunk: acc2 += x1_h @ W2T[:, h*128:+128]  (A=X1H LDS, B global)
        mma_g(smem, OFF_X1H, W2T + (size_t)h * HID, 4 * HID, t, acc2);
        // no barrier: next head's write_c touches H32 only (last read before I),
        // and X1H is next written at agg after 3 intervening barriers.
    }

    // ---- GAT2 epilogue
    write_c(smem, t, acc2);
    __syncthreads();
    {
        const float s0 = as2[lane], s1v = as2[64 + lane];
        const float d0 = ad2[lane], d1v = ad2[64 + lane];
        for (int i = w * 8; i < w * 8 + 8; ++i) {
            const float h0 = hF[i * HID + lane], h1v = hF[i * HID + 64 + lane];
            const float vs = wave_sum(h0 * s0 + h1v * s1v);
            const float vd = wave_sum(h0 * d0 + h1v * d1v);
            if (lane == 0) { sasrc[i] = vs; sadst[i] = vd; }
        }
    }
    __syncthreads();
    {
        const int g8 = t >> 3, sl = t & 7;
        const int b = offs[g8], e = offs[g8 + 1];
        const float sad = sadst[g8];
        float mx = -1e30f;
        for (int i = b + sl; i < e; i += 8) {
            float sc = sasrc[srcs[i]] + sad;
            sc = sc > 0.f ? sc : NEG_SLOPE * sc;
            alpha[i] = sc;
            mx = fmaxf(mx, sc);
        }
#pragma unroll
        for (int o = 1; o < 8; o <<= 1) mx = fmaxf(mx, __shfl_xor(mx, o));
        float den = 0.f;
        for (int i = b + sl; i < e; i += 8) {
            const float ex = __expf(alpha[i] - mx);
            alpha[i] = ex;
            den += ex;
        }
#pragma unroll
        for (int o = 1; o < 8; o <<= 1) den += __shfl_xor(den, o);
        if (sl == 0) sden[g8] = 1.f / (den + 1e-16f);
    }
    __syncthreads();

    // aggregate + mean pool (bias2 after pooling; commutes with mean)
    {
        const int grp = t >> 5, l32 = t & 31, c = l32 * 4;
        float p0 = 0.f, p1 = 0.f, p2 = 0.f, p3 = 0.f;
        for (int d = grp; d < 64; d += 16) {
            const int b = offs[d], e = offs[d + 1];
            const float rd = sden[d];
            float a0 = 0.f, a1 = 0.f, a2 = 0.f, a3 = 0.f;
            for (int i = b; i < e; ++i) {
                const float al = alpha[i];
                const float4 hv = *(const float4*)&hF[(size_t)srcs[i] * HID + c];
                a0 += al * hv.x; a1 += al * hv.y; a2 += al * hv.z; a3 += al * hv.w;
            }
            p0 += a0 * rd; p1 += a1 * rd; p2 += a2 * rd; p3 += a3 * rd;
        }
        float* pool = (float*)(smem + OFF_X1H);     // X1H free (post-barriers)
        *(float4*)&pool[(size_t)grp * HID + c] = make_float4(p0, p1, p2, p3);
    }
    __syncthreads();
    if (t < HID) {
        const float* pool = (const float*)(smem + OFF_X1H);
        float s = 0.f;
#pragma unroll
        for (int i = 0; i < 16; ++i) s += pool[(size_t)i * HID + t];
        out[(size_t)g * HID + t] = s * (1.f / 64.f) + b2[t];
    }
}

// ---------- launch ----------
extern "C" void kernel_launch(void* const* d_in, const int* in_sizes, int n_in,
                              void* d_out, int out_size, void* d_ws, size_t ws_size,
                              hipStream_t stream)
{
    (void)in_sizes; (void)n_in; (void)out_size; (void)ws_size;
    const float* fv        = (const float*)d_in[0];
    const float* W_align   = (const float*)d_in[1];
    const float* b_align   = (const float*)d_in[2];
    const float* ln_gamma  = (const float*)d_in[3];
    const float* ln_beta   = (const float*)d_in[4];
    const float* mask_log  = (const float*)d_in[5];
    const float* W1        = (const float*)d_in[6];
    const float* att_src1  = (const float*)d_in[7];
    const float* att_dst1  = (const float*)d_in[8];
    const float* bias1     = (const float*)d_in[9];
    const float* W2        = (const float*)d_in[10];
    const float* att_src2  = (const float*)d_in[11];
    const float* att_dst2  = (const float*)d_in[12];
    const float* bias2     = (const float*)d_in[13];
    const int*   edge_idx  = (const int*)d_in[14];

    float* out = (float*)d_out;                 // [B*HID] emb, then [64] gate
    f16* W1T = (f16*)d_ws;                      // [4][128][128]
    f16* W2T = W1T + 65536;                     // [128][512]

    k_prep<<<1, EPG, 0, stream>>>(edge_idx);
    k_prepw<<<256, 512, 0, stream>>>(W1, W2, W1T, W2T);
    k_fused<<<B_, NT, 0, stream>>>(fv, W_align, b_align, ln_gamma, ln_beta, mask_log,
                                   W1T, att_src1, att_dst1, bias1,
                                   W2T, att_src2, att_dst2, bias2, out);
}